// Round 6
// baseline (1278.577 us; speedup 1.0000x reference)
//
#include <hip/hip_runtime.h>
#include <stdint.h>

// ---- Problem constants -------------------------------------------------
#define DIM   1536
#define NQ    6272      // 8 * 28 * 28 queries
#define NQP   6400      // padded to 25 * 256
#define NB    50000     // bank rows
#define NBP2  50176     // padded to 196 * 256
#define MT2   25
#define NT2   196
#define GRID2 (MT2 * NT2)
#define NKT   24        // 1536 / 64 K-tiles
#define NIT   12        // NKT / 2 iterations
#define NPIX  (8 * 224 * 224)

typedef __bf16 bf16x8 __attribute__((ext_vector_type(8)));
typedef float  f32x4  __attribute__((ext_vector_type(4)));

__device__ inline unsigned short f2bf(float f) {
  uint32_t u = __float_as_uint(f);
  u += 0x7FFFu + ((u >> 16) & 1u);   // RNE
  return (unsigned short)(u >> 16);
}

__device__ inline void gll16(const unsigned short* g, unsigned short* l) {
  __builtin_amdgcn_global_load_lds(
      (const __attribute__((address_space(1))) uint32_t*)g,
      (__attribute__((address_space(3))) uint32_t*)l, 16, 0, 0);
}

// ---- init: minbits = +inf, image scores = 0 ---------------------------
__global__ void init_kernel(uint32_t* __restrict__ minbits, float* __restrict__ out_scores) {
  int i = blockIdx.x * 256 + threadIdx.x;
  if (i < NQP) minbits[i] = 0x7F800000u;   // +inf
  if (i < 8)   out_scores[i] = 0.0f;
}

// ---- fp32 -> bf16 row conversion + fp32 row norms ---------------------
__global__ void conv_rows(const float* __restrict__ src, unsigned short* __restrict__ dst,
                          float* __restrict__ norms, int nsrc, int ndst) {
  int row  = blockIdx.x * 4 + (threadIdx.x >> 6);
  int lane = threadIdx.x & 63;
  if (row >= ndst) return;
  unsigned short* drow = dst + (size_t)row * DIM;
  if (row < nsrc) {
    const float4* s = (const float4*)(src + (size_t)row * DIM);
    float ns = 0.f;
#pragma unroll
    for (int i = 0; i < 6; ++i) {
      float4 v = s[lane + 64 * i];
      ns += v.x * v.x + v.y * v.y + v.z * v.z + v.w * v.w;
      ushort4 o;
      o.x = f2bf(v.x); o.y = f2bf(v.y); o.z = f2bf(v.z); o.w = f2bf(v.w);
      *(ushort4*)(drow + (lane + 64 * i) * 4) = o;
    }
#pragma unroll
    for (int off = 32; off >= 1; off >>= 1) ns += __shfl_xor(ns, off);
    if (lane == 0) norms[row] = ns;
  } else {
    ushort4 z = {0, 0, 0, 0};
#pragma unroll
    for (int i = 0; i < 6; ++i) *(ushort4*)(drow + (lane + 64 * i) * 4) = z;
    if (lane == 0) norms[row] = 1e30f;   // pad rows never win the min
  }
}

// ---- fused 256x256 8-phase GEMM + column-min --------------------------
// BM=BN=256, BK=64, 512 thr = 8 waves (2M x 4N), per-wave 128x64 out.
// READ-AHEAD pipeline: phase P issues ds_reads for P+1's fragments
// (double-buffered aE/aO, bE/bO); MFMA(P) consumes P-1's reads. LDS pipe
// overlaps matrix pipe. No explicit lgkm waits (compiler emits counted
// lgkmcnt); raw s_barrier (no fence -> no forced drains); per-wave
// vmcnt(0)+BAR gates at ph2/ph6 ends publish staged buffers block-wide.
#define BAR   __builtin_amdgcn_s_barrier()
#define VM0M  asm volatile("s_waitcnt vmcnt(0)" ::: "memory")
#define VM4M  asm volatile("s_waitcnt vmcnt(4)" ::: "memory")
#define PHI   __builtin_amdgcn_s_setprio(1)
#define PLO   __builtin_amdgcn_s_setprio(0)

#define READ_A4(dst, bufI, half, kk) do { \
  _Pragma("unroll") for (int m_ = 0; m_ < 4; ++m_) \
    dst[m_] = *(const bf16x8*)&sA[bufI][wm][(((half) * 4 + m_) * 16 + lr) * 64 + (((kk) * 32 + lk8) ^ lswz)]; \
} while(0)

#define READ_B2(dst, bufI, kk, n0) do { \
  _Pragma("unroll") for (int n_ = 0; n_ < 2; ++n_) \
    dst[(n0) + n_] = *(const bf16x8*)&sB[bufI][bh][(bq * 64 + ((n0) + n_) * 16 + lr) * 64 + (((kk) * 32 + lk8) ^ lswz)]; \
} while(0)

#define MFMA16(half, a4, b4) do { \
  _Pragma("unroll") for (int m_ = 0; m_ < 4; ++m_) \
  _Pragma("unroll") for (int n_ = 0; n_ < 4; ++n_) \
    acc[(half) * 4 + m_][n_] = __builtin_amdgcn_mfma_f32_16x16x32_bf16(a4[m_], b4[n_], acc[(half) * 4 + m_][n_], 0, 0, 0); \
} while(0)

#define STAGE_A(bufI, hI, ktc) do { \
  const unsigned short* _g = gA + (size_t)((hI) * 128 + srow) * DIM + (ktc) + scol; \
  gll16(_g,                     &sA[bufI][hI][sdst]); \
  gll16(_g + (size_t)64 * DIM,  &sA[bufI][hI][4096 + sdst]); \
} while(0)

#define STAGE_B(bufI, hI, ktc) do { \
  const unsigned short* _g = gB + (size_t)((hI) * 128 + srow) * DIM + (ktc) + scol; \
  gll16(_g,                     &sB[bufI][hI][sdst]); \
  gll16(_g + (size_t)64 * DIM,  &sB[bufI][hI][4096 + sdst]); \
} while(0)

// iter i: MFMA tiles 2i (buf0, ph1-4) + 2i+1 (buf1, ph5-8).
// Reads: phase P issues P+1's frags. Stages: ph4 B0', ph5 A0' (tile 2i+2),
// ph8 B1' (tile 2i+3), ph1 A1' (tile 2i+1's A... = current buf1's A).
// Gates: vmcnt(0)+BAR at ph2 end (buf1 ready for ph3+ reads) and ph6 end
// (buf0' ready for ph7+ reads). SN gates next-tile stages; RD gates
// next-iter read-ahead (both 0 on the last iteration).
#define ITER(T0, SN, RD) do { \
  /* ph1 */ READ_A4(aO, 0, 1, 0); READ_B2(bO, 0, 1, 0); \
    STAGE_A(1, 0, (T0) + 64); STAGE_A(1, 1, (T0) + 64); \
    BAR; PHI; MFMA16(0, aE, bE); PLO; BAR; \
  /* ph2 */ READ_A4(aE, 0, 0, 1); READ_B2(bO, 0, 1, 2); \
    BAR; PHI; MFMA16(1, aO, bE); PLO; VM0M; BAR; \
  /* ph3 */ READ_A4(aO, 0, 1, 1); READ_B2(bE, 1, 0, 0); \
    BAR; PHI; MFMA16(0, aE, bO); PLO; BAR; \
  /* ph4 */ READ_A4(aE, 1, 0, 0); READ_B2(bE, 1, 0, 2); \
    if (SN) { STAGE_B(0, 0, (T0) + 128); STAGE_B(0, 1, (T0) + 128); } \
    BAR; PHI; MFMA16(1, aO, bO); PLO; BAR; \
  /* ph5 */ READ_A4(aO, 1, 1, 0); READ_B2(bO, 1, 1, 0); \
    if (SN) { STAGE_A(0, 0, (T0) + 128); STAGE_A(0, 1, (T0) + 128); } \
    BAR; PHI; MFMA16(0, aE, bE); PLO; BAR; \
  /* ph6 */ READ_A4(aE, 1, 0, 1); READ_B2(bO, 1, 1, 2); \
    BAR; PHI; MFMA16(1, aO, bE); PLO; VM0M; BAR; \
  /* ph7 */ READ_A4(aO, 1, 1, 1); if (RD) { READ_B2(bE, 0, 0, 0); } \
    BAR; PHI; MFMA16(0, aE, bO); PLO; BAR; \
  /* ph8 */ if (RD) { READ_A4(aE, 0, 0, 0); READ_B2(bE, 0, 0, 2); } \
    if (SN) { STAGE_B(1, 0, (T0) + 192); STAGE_B(1, 1, (T0) + 192); } \
    BAR; PHI; MFMA16(1, aO, bO); PLO; BAR; \
} while(0)

__global__ __launch_bounds__(512, 2)
void gemm_min8(const unsigned short* __restrict__ fA, const unsigned short* __restrict__ bB,
               const float* __restrict__ bn, uint32_t* __restrict__ minbits) {
  __shared__ unsigned short sA[2][2][8192];   // 64 KiB
  __shared__ unsigned short sB[2][2][8192];   // 64 KiB

  const int nwg = GRID2;
  int bid = blockIdx.x;
  const int qch = nwg >> 3, rch = nwg & 7;
  int xcd = bid & 7, loc = bid >> 3;
  int swz = (xcd < rch ? xcd * (qch + 1) : rch * (qch + 1) + (xcd - rch) * qch) + loc;
  int mt = swz % MT2;            // M-fast: consecutive blocks share the B (bank) panel
  int nt = swz / MT2;

  int tid = threadIdx.x;
  int lane = tid & 63, wave = tid >> 6;
  int wm = wave >> 2, wn = wave & 3, bq = wn & 1, bh = wn >> 1;
  int lr = lane & 15, lk8 = (lane >> 4) * 8;
  int lswz = (lane & 7) << 3;    // XOR on 16B-slot bits (ushort units)

  const unsigned short* gA = fA + (size_t)(mt * 256) * DIM;
  const unsigned short* gB = bB + (size_t)(nt * 256) * DIM;

  int srow = tid >> 3;                                    // 0..63
  int scol = ((tid & 7) * 8) ^ (((tid >> 3) & 7) << 3);   // pre-swizzled source col (bf16)
  int sdst = tid * 8;                                     // linear LDS dest (ushort)

  f32x4 acc[8][4] = {};
  bf16x8 aE[4], aO[4], bE[4], bO[4];

  // prologue: tile0 full into buf0 (8 loads/thr); tile1 B into buf1 (4)
  STAGE_A(0, 0, 0); STAGE_A(0, 1, 0);
  STAGE_B(0, 0, 0); STAGE_B(0, 1, 0);
  STAGE_B(1, 0, 64); STAGE_B(1, 1, 64);
  VM4M; BAR;                         // tile0 landed block-wide; B1 in flight
  READ_A4(aE, 0, 0, 0);              // ph1 frags: buf0 h0k0
  READ_B2(bE, 0, 0, 0); READ_B2(bE, 0, 0, 2);

#pragma unroll 1
  for (int i = 0; i < NIT - 1; ++i) {
    ITER(i * 128, 1, 1);
  }
  ITER((NIT - 1) * 128, 0, 0);       // tiles 22,23: no stages, no read-ahead

  // epilogue: per-row min over this tile's 256 columns of (bn - 2*dot)
  float bnv[4];
#pragma unroll
  for (int n_ = 0; n_ < 4; ++n_)
    bnv[n_] = bn[nt * 256 + wn * 64 + n_ * 16 + lr];
  int qbase = mt * 256 + wm * 128;
#pragma unroll
  for (int m_ = 0; m_ < 8; ++m_) {
#pragma unroll
    for (int r = 0; r < 4; ++r) {
      float v = bnv[0] - 2.0f * acc[m_][0][r];
      v = fminf(v, bnv[1] - 2.0f * acc[m_][1][r]);
      v = fminf(v, bnv[2] - 2.0f * acc[m_][2][r]);
      v = fminf(v, bnv[3] - 2.0f * acc[m_][3][r]);
      // C/D layout: col = lane&15, row = (lane>>4)*4 + r
      v = fminf(v, __shfl_xor(v, 1));
      v = fminf(v, __shfl_xor(v, 2));
      v = fminf(v, __shfl_xor(v, 4));
      v = fminf(v, __shfl_xor(v, 8));
      if (lr == 0) {
        int q = qbase + m_ * 16 + (lane >> 4) * 4 + r;
        atomicMin(&minbits[q], __float_as_uint(v));  // positive floats: uint order == float order
      }
    }
  }
}

// ---- patch scores + per-image max -------------------------------------
__global__ void scores_kernel(const uint32_t* __restrict__ minbits, const float* __restrict__ qn,
                              float* __restrict__ ps, float* __restrict__ img) {
  int q = blockIdx.x * 256 + threadIdx.x;
  if (q >= NQ) return;
  float s = __uint_as_float(minbits[q]) + qn[q];
  ps[q] = s;
  atomicMax((uint32_t*)&img[q / 784], __float_as_uint(s));  // scores > 0
}

// ---- bilinear 28x28 -> 224x224 (half-pixel centers, edge clamp) -------
__global__ void resize_kernel(const float* __restrict__ ps, float* __restrict__ masks) {
  int idx = blockIdx.x * 256 + threadIdx.x;
  if (idx >= NPIX) return;
  int b   = idx / (224 * 224);
  int rem = idx - b * (224 * 224);
  int oy  = rem / 224;
  int ox  = rem - oy * 224;
  float sy = (oy + 0.5f) * 0.125f - 0.5f;
  float sx = (ox + 0.5f) * 0.125f - 0.5f;
  float fy0 = floorf(sy), fx0 = floorf(sx);
  int y0 = (int)fy0, x0 = (int)fx0;
  float fy = sy - fy0, fx = sx - fx0;
  int y0c = min(max(y0, 0), 27),     y1c = min(max(y0 + 1, 0), 27);
  int x0c = min(max(x0, 0), 27),     x1c = min(max(x0 + 1, 0), 27);
  const float* p = ps + b * 784;
  float top = p[y0c * 28 + x0c] * (1.f - fx) + p[y0c * 28 + x1c] * fx;
  float bot = p[y1c * 28 + x0c] * (1.f - fx) + p[y1c * 28 + x1c] * fx;
  masks[idx] = top * (1.f - fy) + bot * fy;
}

// ---- host launch -------------------------------------------------------
extern "C" void kernel_launch(void* const* d_in, const int* in_sizes, int n_in,
                              void* d_out, int out_size, void* d_ws, size_t ws_size,
                              hipStream_t stream) {
  const float* features = (const float*)d_in[0];   // [6272, 1536]
  const float* bank     = (const float*)d_in[1];   // [50000, 1536]

  char* ws = (char*)d_ws;
  size_t off = 0;
  unsigned short* bankB = (unsigned short*)(ws + off); off += (size_t)NBP2 * DIM * 2;  // 154.1 MB
  unsigned short* featB = (unsigned short*)(ws + off); off += (size_t)NQP * DIM * 2;   // 19.7 MB
  float*    bn      = (float*)(ws + off);    off += (size_t)NBP2 * 4;
  float*    qn      = (float*)(ws + off);    off += (size_t)NQP * 4;
  uint32_t* minbits = (uint32_t*)(ws + off); off += (size_t)NQP * 4;
  float*    ps      = (float*)(ws + off);    off += (size_t)NQ * 4;

  float* out_scores = (float*)d_out;       // [8]
  float* masks      = out_scores + 8;      // [8,224,224]

  hipLaunchKernelGGL(init_kernel, dim3(25), dim3(256), 0, stream, minbits, out_scores);
  hipLaunchKernelGGL(conv_rows, dim3(NBP2 / 4), dim3(256), 0, stream, bank, bankB, bn, NB, NBP2);
  hipLaunchKernelGGL(conv_rows, dim3(NQP / 4), dim3(256), 0, stream, features, featB, qn, NQ, NQP);
  hipLaunchKernelGGL(gemm_min8, dim3(GRID2), dim3(512), 0, stream, featB, bankB, bn, minbits);
  hipLaunchKernelGGL(scores_kernel, dim3(25), dim3(256), 0, stream, minbits, qn, ps, out_scores);
  hipLaunchKernelGGL(resize_kernel, dim3((NPIX + 255) / 256), dim3(256), 0, stream, ps, masks);
}

// Round 7
// 1235.382 us; speedup vs baseline: 1.0350x; 1.0350x over previous
//
#include <hip/hip_runtime.h>
#include <stdint.h>

// ---- Problem constants -------------------------------------------------
#define DIM   1536
#define NQ    6272      // 8 * 28 * 28 queries
#define NQP   6400      // padded to 25 * 256
#define NB    50000     // bank rows
#define NBP2  50176     // padded to 196 * 256
#define MT2   25
#define NT2   196
#define GRID2 (MT2 * NT2)
#define NKT   24        // 1536 / 64 K-tiles
#define NIT   12        // NKT / 2 iterations
#define NPIX  (8 * 224 * 224)

typedef __bf16 bf16x8 __attribute__((ext_vector_type(8)));
typedef float  f32x4  __attribute__((ext_vector_type(4)));

__device__ inline unsigned short f2bf(float f) {
  uint32_t u = __float_as_uint(f);
  u += 0x7FFFu + ((u >> 16) & 1u);   // RNE
  return (unsigned short)(u >> 16);
}

__device__ inline void gll16(const unsigned short* g, unsigned short* l) {
  __builtin_amdgcn_global_load_lds(
      (const __attribute__((address_space(1))) uint32_t*)g,
      (__attribute__((address_space(3))) uint32_t*)l, 16, 0, 0);
}

// ---- init: minbits = +inf, image scores = 0 ---------------------------
__global__ void init_kernel(uint32_t* __restrict__ minbits, float* __restrict__ out_scores) {
  int i = blockIdx.x * 256 + threadIdx.x;
  if (i < NQP) minbits[i] = 0x7F800000u;   // +inf
  if (i < 8)   out_scores[i] = 0.0f;
}

// ---- fp32 -> bf16 row conversion + fp32 row norms ---------------------
__global__ void conv_rows(const float* __restrict__ src, unsigned short* __restrict__ dst,
                          float* __restrict__ norms, int nsrc, int ndst) {
  int row  = blockIdx.x * 4 + (threadIdx.x >> 6);
  int lane = threadIdx.x & 63;
  if (row >= ndst) return;
  unsigned short* drow = dst + (size_t)row * DIM;
  if (row < nsrc) {
    const float4* s = (const float4*)(src + (size_t)row * DIM);
    float ns = 0.f;
#pragma unroll
    for (int i = 0; i < 6; ++i) {
      float4 v = s[lane + 64 * i];
      ns += v.x * v.x + v.y * v.y + v.z * v.z + v.w * v.w;
      ushort4 o;
      o.x = f2bf(v.x); o.y = f2bf(v.y); o.z = f2bf(v.z); o.w = f2bf(v.w);
      *(ushort4*)(drow + (lane + 64 * i) * 4) = o;
    }
#pragma unroll
    for (int off = 32; off >= 1; off >>= 1) ns += __shfl_xor(ns, off);
    if (lane == 0) norms[row] = ns;
  } else {
    ushort4 z = {0, 0, 0, 0};
#pragma unroll
    for (int i = 0; i < 6; ++i) *(ushort4*)(drow + (lane + 64 * i) * 4) = z;
    if (lane == 0) norms[row] = 1e30f;   // pad rows never win the min
  }
}

// ---- fused 256x256 8-phase GEMM + column-min --------------------------
// BM=BN=256, BK=64, 512 thr = 8 waves (2M x 4N), per-wave 128x64 out.
// SINGLE barrier per phase; lgkmcnt(0) drains reads BEFORE the barrier;
// MFMA issues AFTER the barrier and overlaps the next phase's reads/stages.
// vmcnt(2) gates only at ph4/ph8 (exact RAW count; slack >= 2 phases).
#define BAR   asm volatile("s_barrier" ::: "memory")
#define LGKM0 asm volatile("s_waitcnt lgkmcnt(0)" ::: "memory")
#define VM2   asm volatile("s_waitcnt vmcnt(2)" ::: "memory")
#define VM0   asm volatile("s_waitcnt vmcnt(0)" ::: "memory")
#define PHI   __builtin_amdgcn_s_setprio(1)
#define PLO   __builtin_amdgcn_s_setprio(0)

#define READ_A4(dst, bufI, half, kk) do { \
  _Pragma("unroll") for (int m_ = 0; m_ < 4; ++m_) \
    dst[m_] = *(const bf16x8*)&sA[bufI][wm][(((half) * 4 + m_) * 16 + lr) * 64 + (((kk) * 32 + lk8) ^ lswz)]; \
} while(0)

#define READ_B4(dst, bufI, kk) do { \
  _Pragma("unroll") for (int n_ = 0; n_ < 4; ++n_) \
    dst[n_] = *(const bf16x8*)&sB[bufI][bh][(bq * 64 + n_ * 16 + lr) * 64 + (((kk) * 32 + lk8) ^ lswz)]; \
} while(0)

#define MFMA16(half, a4, b4) do { \
  _Pragma("unroll") for (int m_ = 0; m_ < 4; ++m_) \
  _Pragma("unroll") for (int n_ = 0; n_ < 4; ++n_) \
    acc[(half) * 4 + m_][n_] = __builtin_amdgcn_mfma_f32_16x16x32_bf16(a4[m_], b4[n_], acc[(half) * 4 + m_][n_], 0, 0, 0); \
} while(0)

#define STAGE_A(bufI, hI, ktc) do { \
  const unsigned short* _g = gA + (size_t)((hI) * 128 + srow) * DIM + (ktc) + scol; \
  gll16(_g,                     &sA[bufI][hI][sdst]); \
  gll16(_g + (size_t)64 * DIM,  &sA[bufI][hI][4096 + sdst]); \
} while(0)

#define STAGE_B(bufI, hI, ktc) do { \
  const unsigned short* _g = gB + (size_t)((hI) * 128 + srow) * DIM + (ktc) + scol; \
  gll16(_g,                     &sB[bufI][hI][sdst]); \
  gll16(_g + (size_t)64 * DIM,  &sB[bufI][hI][4096 + sdst]); \
} while(0)

// iter i: tiles 2i (buf0, ph1-4) + 2i+1 (buf1, ph5-8); k-half phases.
// Stages: ph1 B(1,1)+A(1,0), ph2 A(1,1) [tile 2i+1]; ph4 B(0,0),
// ph5 B(0,1)+A(0,0), ph6 A(0,1) [tile 2i+2]; ph8 B(1,0) [tile 2i+3].
// WAR: every staged region's last reader drained >=1 barrier earlier.
// RAW: VM2 at ph4 (allows ph4's own B(0,0) in flight) and ph8 (allows B(1,0)).
#define ITER(T0, SN, VML) do { \
  { bf16x8 a4[4]; READ_A4(a4, 0, 0, 0); READ_B4(bk, 0, 0); \
    STAGE_B(1, 1, (T0) + 64); STAGE_A(1, 0, (T0) + 64); \
    LGKM0; BAR; PHI; MFMA16(0, a4, bk); PLO; } \
  { bf16x8 a4[4]; READ_A4(a4, 0, 1, 0); STAGE_A(1, 1, (T0) + 64); \
    LGKM0; BAR; PHI; MFMA16(1, a4, bk); PLO; } \
  { bf16x8 a4[4]; READ_A4(a4, 0, 0, 1); READ_B4(bk, 0, 1); \
    LGKM0; BAR; PHI; MFMA16(0, a4, bk); PLO; } \
  { bf16x8 a4[4]; READ_A4(a4, 0, 1, 1); if (SN) STAGE_B(0, 0, (T0) + 128); \
    LGKM0; VML; BAR; PHI; MFMA16(1, a4, bk); PLO; } \
  { bf16x8 a4[4]; READ_A4(a4, 1, 0, 0); READ_B4(bk, 1, 0); \
    if (SN) { STAGE_B(0, 1, (T0) + 128); STAGE_A(0, 0, (T0) + 128); } \
    LGKM0; BAR; PHI; MFMA16(0, a4, bk); PLO; } \
  { bf16x8 a4[4]; READ_A4(a4, 1, 1, 0); if (SN) STAGE_A(0, 1, (T0) + 128); \
    LGKM0; BAR; PHI; MFMA16(1, a4, bk); PLO; } \
  { bf16x8 a4[4]; READ_A4(a4, 1, 0, 1); READ_B4(bk, 1, 1); \
    LGKM0; BAR; PHI; MFMA16(0, a4, bk); PLO; } \
  { bf16x8 a4[4]; READ_A4(a4, 1, 1, 1); if (SN) STAGE_B(1, 0, (T0) + 192); \
    LGKM0; VML; BAR; PHI; MFMA16(1, a4, bk); PLO; } \
} while(0)

__global__ __launch_bounds__(512, 2)
void gemm_min8(const unsigned short* __restrict__ fA, const unsigned short* __restrict__ bB,
               const float* __restrict__ bn, uint32_t* __restrict__ minbits) {
  __shared__ unsigned short sA[2][2][8192];   // 64 KiB
  __shared__ unsigned short sB[2][2][8192];   // 64 KiB

  const int nwg = GRID2;
  int bid = blockIdx.x;
  const int qch = nwg >> 3, rch = nwg & 7;
  int xcd = bid & 7, loc = bid >> 3;
  int swz = (xcd < rch ? xcd * (qch + 1) : rch * (qch + 1) + (xcd - rch) * qch) + loc;
  int mt = swz % MT2;            // M-fast: consecutive blocks share the B (bank) panel
  int nt = swz / MT2;

  int tid = threadIdx.x;
  int lane = tid & 63, wave = tid >> 6;
  int wm = wave >> 2, wn = wave & 3, bq = wn & 1, bh = wn >> 1;
  int lr = lane & 15, lk8 = (lane >> 4) * 8;
  int lswz = (lane & 7) << 3;    // XOR on 16B-slot bits (ushort units)

  const unsigned short* gA = fA + (size_t)(mt * 256) * DIM;
  const unsigned short* gB = bB + (size_t)(nt * 256) * DIM;

  int srow = tid >> 3;                                    // 0..63
  int scol = ((tid & 7) * 8) ^ (((tid >> 3) & 7) << 3);   // pre-swizzled source col (bf16)
  int sdst = tid * 8;                                     // linear LDS dest (ushort)

  f32x4 acc[8][4] = {};
  bf16x8 bk[4];

  // prologue: tile0 full into buf0; tile1.B0 into buf1
  STAGE_A(0, 0, 0); STAGE_A(0, 1, 0);
  STAGE_B(0, 0, 0); STAGE_B(0, 1, 0);
  STAGE_B(1, 0, 64);
  VM2; BAR;                      // buf0's 8 loads retired; B(1,0) may stay in flight

#pragma unroll 1
  for (int i = 0; i < NIT - 1; ++i) {
    ITER(i * 128, 1, VM2);
  }
  ITER((NIT - 1) * 128, 0, VM0);   // tiles 22,23: no next-tile stages; drain at gates

  // epilogue: per-row min over this tile's 256 columns of (bn - 2*dot)
  float bnv[4];
#pragma unroll
  for (int n_ = 0; n_ < 4; ++n_)
    bnv[n_] = bn[nt * 256 + wn * 64 + n_ * 16 + lr];
  int qbase = mt * 256 + wm * 128;
#pragma unroll
  for (int m_ = 0; m_ < 8; ++m_) {
#pragma unroll
    for (int r = 0; r < 4; ++r) {
      float v = bnv[0] - 2.0f * acc[m_][0][r];
      v = fminf(v, bnv[1] - 2.0f * acc[m_][1][r]);
      v = fminf(v, bnv[2] - 2.0f * acc[m_][2][r]);
      v = fminf(v, bnv[3] - 2.0f * acc[m_][3][r]);
      // C/D layout: col = lane&15, row = (lane>>4)*4 + r
      v = fminf(v, __shfl_xor(v, 1));
      v = fminf(v, __shfl_xor(v, 2));
      v = fminf(v, __shfl_xor(v, 4));
      v = fminf(v, __shfl_xor(v, 8));
      if (lr == 0) {
        int q = qbase + m_ * 16 + (lane >> 4) * 4 + r;
        atomicMin(&minbits[q], __float_as_uint(v));  // positive floats: uint order == float order
      }
    }
  }
}

// ---- patch scores + per-image max -------------------------------------
__global__ void scores_kernel(const uint32_t* __restrict__ minbits, const float* __restrict__ qn,
                              float* __restrict__ ps, float* __restrict__ img) {
  int q = blockIdx.x * 256 + threadIdx.x;
  if (q >= NQ) return;
  float s = __uint_as_float(minbits[q]) + qn[q];
  ps[q] = s;
  atomicMax((uint32_t*)&img[q / 784], __float_as_uint(s));  // scores > 0
}

// ---- bilinear 28x28 -> 224x224 (half-pixel centers, edge clamp) -------
__global__ void resize_kernel(const float* __restrict__ ps, float* __restrict__ masks) {
  int idx = blockIdx.x * 256 + threadIdx.x;
  if (idx >= NPIX) return;
  int b   = idx / (224 * 224);
  int rem = idx - b * (224 * 224);
  int oy  = rem / 224;
  int ox  = rem - oy * 224;
  float sy = (oy + 0.5f) * 0.125f - 0.5f;
  float sx = (ox + 0.5f) * 0.125f - 0.5f;
  float fy0 = floorf(sy), fx0 = floorf(sx);
  int y0 = (int)fy0, x0 = (int)fx0;
  float fy = sy - fy0, fx = sx - fx0;
  int y0c = min(max(y0, 0), 27),     y1c = min(max(y0 + 1, 0), 27);
  int x0c = min(max(x0, 0), 27),     x1c = min(max(x0 + 1, 0), 27);
  const float* p = ps + b * 784;
  float top = p[y0c * 28 + x0c] * (1.f - fx) + p[y0c * 28 + x1c] * fx;
  float bot = p[y1c * 28 + x0c] * (1.f - fx) + p[y1c * 28 + x1c] * fx;
  masks[idx] = top * (1.f - fy) + bot * fy;
}

// ---- host launch -------------------------------------------------------
extern "C" void kernel_launch(void* const* d_in, const int* in_sizes, int n_in,
                              void* d_out, int out_size, void* d_ws, size_t ws_size,
                              hipStream_t stream) {
  const float* features = (const float*)d_in[0];   // [6272, 1536]
  const float* bank     = (const float*)d_in[1];   // [50000, 1536]

  char* ws = (char*)d_ws;
  size_t off = 0;
  unsigned short* bankB = (unsigned short*)(ws + off); off += (size_t)NBP2 * DIM * 2;  // 154.1 MB
  unsigned short* featB = (unsigned short*)(ws + off); off += (size_t)NQP * DIM * 2;   // 19.7 MB
  float*    bn      = (float*)(ws + off);    off += (size_t)NBP2 * 4;
  float*    qn      = (float*)(ws + off);    off += (size_t)NQP * 4;
  uint32_t* minbits = (uint32_t*)(ws + off); off += (size_t)NQP * 4;
  float*    ps      = (float*)(ws + off);    off += (size_t)NQ * 4;

  float* out_scores = (float*)d_out;       // [8]
  float* masks      = out_scores + 8;      // [8,224,224]

  hipLaunchKernelGGL(init_kernel, dim3(25), dim3(256), 0, stream, minbits, out_scores);
  hipLaunchKernelGGL(conv_rows, dim3(NBP2 / 4), dim3(256), 0, stream, bank, bankB, bn, NB, NBP2);
  hipLaunchKernelGGL(conv_rows, dim3(NQP / 4), dim3(256), 0, stream, features, featB, qn, NQ, NQP);
  hipLaunchKernelGGL(gemm_min8, dim3(GRID2), dim3(512), 0, stream, featB, bankB, bn, minbits);
  hipLaunchKernelGGL(scores_kernel, dim3(25), dim3(256), 0, stream, minbits, qn, ps, out_scores);
  hipLaunchKernelGGL(resize_kernel, dim3((NPIX + 255) / 256), dim3(256), 0, stream, ps, masks);
}

// Round 9
// 960.932 us; speedup vs baseline: 1.3306x; 1.2856x over previous
//
#include <hip/hip_runtime.h>
#include <stdint.h>

// ---- Problem constants -------------------------------------------------
#define DIM   1536
#define NQ    6272      // 8 * 28 * 28 queries
#define NQP   6400      // padded to 25 * 256
#define NB    50000     // bank rows
#define NBP2  50176     // padded to 196 * 256
#define MT2   25
#define NT2   196
#define GRID2 (MT2 * NT2)
#define NKT   24        // 1536 / 64 K-tiles
#define NIT   12        // NKT / 2 iterations
#define NPIX  (8 * 224 * 224)

typedef __bf16 bf16x8 __attribute__((ext_vector_type(8)));
typedef float  f32x4  __attribute__((ext_vector_type(4)));
typedef __attribute__((address_space(3))) unsigned short lds_us;

__device__ inline unsigned short f2bf(float f) {
  uint32_t u = __float_as_uint(f);
  u += 0x7FFFu + ((u >> 16) & 1u);   // RNE
  return (unsigned short)(u >> 16);
}

__device__ inline void gll16(const unsigned short* g, unsigned short* l) {
  __builtin_amdgcn_global_load_lds(
      (const __attribute__((address_space(1))) uint32_t*)g,
      (__attribute__((address_space(3))) uint32_t*)l, 16, 0, 0);
}

// ---- init: minbits = +inf, image scores = 0 ---------------------------
__global__ void init_kernel(uint32_t* __restrict__ minbits, float* __restrict__ out_scores) {
  int i = blockIdx.x * 256 + threadIdx.x;
  if (i < NQP) minbits[i] = 0x7F800000u;   // +inf
  if (i < 8)   out_scores[i] = 0.0f;
}

// ---- fp32 -> bf16 row conversion + fp32 row norms ---------------------
__global__ void conv_rows(const float* __restrict__ src, unsigned short* __restrict__ dst,
                          float* __restrict__ norms, int nsrc, int ndst) {
  int row  = blockIdx.x * 4 + (threadIdx.x >> 6);
  int lane = threadIdx.x & 63;
  if (row >= ndst) return;
  unsigned short* drow = dst + (size_t)row * DIM;
  if (row < nsrc) {
    const float4* s = (const float4*)(src + (size_t)row * DIM);
    float ns = 0.f;
#pragma unroll
    for (int i = 0; i < 6; ++i) {
      float4 v = s[lane + 64 * i];
      ns += v.x * v.x + v.y * v.y + v.z * v.z + v.w * v.w;
      ushort4 o;
      o.x = f2bf(v.x); o.y = f2bf(v.y); o.z = f2bf(v.z); o.w = f2bf(v.w);
      *(ushort4*)(drow + (lane + 64 * i) * 4) = o;
    }
#pragma unroll
    for (int off = 32; off >= 1; off >>= 1) ns += __shfl_xor(ns, off);
    if (lane == 0) norms[row] = ns;
  } else {
    ushort4 z = {0, 0, 0, 0};
#pragma unroll
    for (int i = 0; i < 6; ++i) *(ushort4*)(drow + (lane + 64 * i) * 4) = z;
    if (lane == 0) norms[row] = 1e30f;   // pad rows never win the min
  }
}

// ---- fused 256x256 8-phase GEMM + column-min --------------------------
// BM=BN=256, BK=64, 512 thr = 8 waves (2M x 4N), per-wave 128x64 out.
// Counted-lgkm pipeline, publish-correct: phase P issues asm ds_reads for
// P+1 right AFTER a barrier (whose preceding gate covered the staged data),
// stages, waits lgkmcnt(n=just-issued) (drains only P's frags), barrier,
// then MFMA(P) runs while P+1's reads are serviced by the LDS pipe.
#define BAR   asm volatile("s_barrier" ::: "memory")
#define LGKM(n) do { asm volatile("s_waitcnt lgkmcnt(" #n ")" ::: "memory"); \
                     __builtin_amdgcn_sched_barrier(0); } while(0)
#define VM0   asm volatile("s_waitcnt vmcnt(0)" ::: "memory")
#define VM4   asm volatile("s_waitcnt vmcnt(4)" ::: "memory")
#define PHI   __builtin_amdgcn_s_setprio(1)
#define PLO   __builtin_amdgcn_s_setprio(0)

// ds_read_b128 with base VGPR + compile-time immediate offset (zero VALU)
#define DSR(dst, base, imm) \
  asm volatile("ds_read_b128 %0, %1 offset:%2" : "=v"(dst) : "v"(base), "i"(imm))

// A frag quad (rows (half*4+m)*16+lr of sA[buf][wm]); bytes: buf*32768+half*8192+m*2048
#define READ_A4A(dst, bufI, half, kk) do { \
  DSR(dst[0], ((kk) ? aOffO : aOffE), (bufI) * 32768 + (half) * 8192 + 0);    \
  DSR(dst[1], ((kk) ? aOffO : aOffE), (bufI) * 32768 + (half) * 8192 + 2048); \
  DSR(dst[2], ((kk) ? aOffO : aOffE), (bufI) * 32768 + (half) * 8192 + 4096); \
  DSR(dst[3], ((kk) ? aOffO : aOffE), (bufI) * 32768 + (half) * 8192 + 6144); \
} while(0)

// B frag quad (rows bq*64+n*16+lr of sB[buf][bh]); bytes: buf*32768+n*2048
#define READ_B4A(dst, bufI, kk) do { \
  DSR(dst[0], ((kk) ? bOffO : bOffE), (bufI) * 32768 + 0);    \
  DSR(dst[1], ((kk) ? bOffO : bOffE), (bufI) * 32768 + 2048); \
  DSR(dst[2], ((kk) ? bOffO : bOffE), (bufI) * 32768 + 4096); \
  DSR(dst[3], ((kk) ? bOffO : bOffE), (bufI) * 32768 + 6144); \
} while(0)

#define MFMA16(half, a4, b4) do { \
  _Pragma("unroll") for (int m_ = 0; m_ < 4; ++m_) \
  _Pragma("unroll") for (int n_ = 0; n_ < 4; ++n_) \
    acc[(half) * 4 + m_][n_] = __builtin_amdgcn_mfma_f32_16x16x32_bf16( \
      __builtin_bit_cast(bf16x8, a4[m_]), __builtin_bit_cast(bf16x8, b4[n_]), \
      acc[(half) * 4 + m_][n_], 0, 0, 0); \
} while(0)

#define STAGE_A(bufI, hI, ktc) do { \
  const unsigned short* _g = gA + (size_t)((hI) * 128 + srow) * DIM + (ktc) + scol; \
  gll16(_g,                     &sA[bufI][hI][sdst]); \
  gll16(_g + (size_t)64 * DIM,  &sA[bufI][hI][4096 + sdst]); \
} while(0)

#define STAGE_B(bufI, hI, ktc) do { \
  const unsigned short* _g = gB + (size_t)((hI) * 128 + srow) * DIM + (ktc) + scol; \
  gll16(_g,                     &sB[bufI][hI][sdst]); \
  gll16(_g + (size_t)64 * DIM,  &sB[bufI][hI][4096 + sdst]); \
} while(0)

// iter i: MFMA tiles 2i (buf0, ph1-4) + 2i+1 (buf1, ph5-8); reads 1 phase
// ahead (banks aX/aY, bE/bO). Stages: ph1 A(1) [tile 2i+1], ph4 B(0)',
// ph5 A(0)' [tile 2i+2], ph8 B(1)' [tile 2i+3]. Gates: VM0 at ph3 (covers
// ph8'+ph1 stages; buf1 published for ph4 reads) and ph7 (covers ph4+ph5;
// buf0' published for ph8 reads). All reads post-barrier => publish-safe.
// Every stage >=1 barrier after its region's reads drained (WAR-safe).
#define ITER(T0, SN, RD) do { \
  /* ph1: rd A(0,h1,k0) */ READ_A4A(aY, 0, 1, 0); \
    STAGE_A(1, 0, (T0) + 64); STAGE_A(1, 1, (T0) + 64); \
    LGKM(4); BAR; PHI; MFMA16(0, aX, bE); PLO; \
  /* ph2: rd A(0,h0,k1)+B(0,k1) */ READ_A4A(aX, 0, 0, 1); READ_B4A(bO, 0, 1); \
    LGKM(8); BAR; PHI; MFMA16(1, aY, bE); PLO; \
  /* ph3: rd A(0,h1,k1) */ READ_A4A(aY, 0, 1, 1); \
    LGKM(4); VM0; BAR; PHI; MFMA16(0, aX, bO); PLO; \
  /* ph4: rd A(1,h0,k0)+B(1,k0) */ READ_A4A(aX, 1, 0, 0); READ_B4A(bE, 1, 0); \
    if (SN) { STAGE_B(0, 0, (T0) + 128); STAGE_B(0, 1, (T0) + 128); } \
    LGKM(8); BAR; PHI; MFMA16(1, aY, bO); PLO; \
  /* ph5: rd A(1,h1,k0) */ READ_A4A(aY, 1, 1, 0); \
    if (SN) { STAGE_A(0, 0, (T0) + 128); STAGE_A(0, 1, (T0) + 128); } \
    LGKM(4); BAR; PHI; MFMA16(0, aX, bE); PLO; \
  /* ph6: rd A(1,h0,k1)+B(1,k1) */ READ_A4A(aX, 1, 0, 1); READ_B4A(bO, 1, 1); \
    LGKM(8); BAR; PHI; MFMA16(1, aY, bE); PLO; \
  /* ph7: rd A(1,h1,k1) */ READ_A4A(aY, 1, 1, 1); \
    LGKM(4); VM0; BAR; PHI; MFMA16(0, aX, bO); PLO; \
  /* ph8: rd next A(0,h0,k0)+B(0,k0) */ \
    if (RD) { READ_A4A(aX, 0, 0, 0); READ_B4A(bE, 0, 0); } \
    if (SN) { STAGE_B(1, 0, (T0) + 192); STAGE_B(1, 1, (T0) + 192); } \
    if (RD) { LGKM(8); } else { LGKM(0); } \
    BAR; PHI; MFMA16(1, aY, bO); PLO; \
} while(0)

__global__ __launch_bounds__(512, 2)
void gemm_min8(const unsigned short* __restrict__ fA, const unsigned short* __restrict__ bB,
               const float* __restrict__ bn, uint32_t* __restrict__ minbits) {
  __shared__ unsigned short sA[2][2][8192];   // 64 KiB
  __shared__ unsigned short sB[2][2][8192];   // 64 KiB

  const int nwg = GRID2;
  int bid = blockIdx.x;
  const int qch = nwg >> 3, rch = nwg & 7;
  int xcd = bid & 7, loc = bid >> 3;
  int swz = (xcd < rch ? xcd * (qch + 1) : rch * (qch + 1) + (xcd - rch) * qch) + loc;
  int mt = swz % MT2;            // M-fast: consecutive blocks share the B (bank) panel
  int nt = swz / MT2;

  int tid = threadIdx.x;
  int lane = tid & 63, wave = tid >> 6;
  int wm = wave >> 2, wn = wave & 3, bq = wn & 1, bh = wn >> 1;
  int lr = lane & 15, lk8 = (lane >> 4) * 8;
  int lswz = (lane & 7) << 3;    // XOR on 16B-slot bits (ushort units)

  const unsigned short* gA = fA + (size_t)(mt * 256) * DIM;
  const unsigned short* gB = bB + (size_t)(nt * 256) * DIM;

  int srow = tid >> 3;                                    // 0..63
  int scol = ((tid & 7) * 8) ^ (((tid >> 3) & 7) << 3);   // pre-swizzled source col (bf16)
  int sdst = tid * 8;                                     // linear LDS dest (ushort)

  // 32-bit LDS byte-offset bases for asm ds_read (E: kk=0, O: kk=1)
  uint32_t aOffE = (uint32_t)(uintptr_t)(lds_us*)&sA[0][wm][lr * 64 + (lk8 ^ lswz)];
  uint32_t aOffO = (uint32_t)(uintptr_t)(lds_us*)&sA[0][wm][lr * 64 + ((32 + lk8) ^ lswz)];
  uint32_t bOffE = (uint32_t)(uintptr_t)(lds_us*)&sB[0][bh][(bq * 64 + lr) * 64 + (lk8 ^ lswz)];
  uint32_t bOffO = (uint32_t)(uintptr_t)(lds_us*)&sB[0][bh][(bq * 64 + lr) * 64 + ((32 + lk8) ^ lswz)];

  f32x4 acc[8][4] = {};
  f32x4 aX[4], aY[4], bE[4], bO[4];

  // prologue: tile0 -> buf0 (8 gll16); tile1 B -> buf1 (4 gll16);
  // gate own 8 (VM4), barrier (publish), then pre-read ph1's fragments.
  STAGE_A(0, 0, 0); STAGE_A(0, 1, 0);
  STAGE_B(0, 0, 0); STAGE_B(0, 1, 0);
  STAGE_B(1, 0, 64); STAGE_B(1, 1, 64);
  VM4; BAR;
  READ_A4A(aX, 0, 0, 0); READ_B4A(bE, 0, 0);   // drained by ph1's LGKM(4)

#pragma unroll 1
  for (int i = 0; i < NIT - 1; ++i) {
    ITER(i * 128, 1, 1);
  }
  ITER((NIT - 1) * 128, 0, 0);   // tiles 22,23: no next-tile stages/read-ahead

  // epilogue: per-row min over this tile's 256 columns of (bn - 2*dot)
  float bnv[4];
#pragma unroll
  for (int n_ = 0; n_ < 4; ++n_)
    bnv[n_] = bn[nt * 256 + wn * 64 + n_ * 16 + lr];
  int qbase = mt * 256 + wm * 128;
#pragma unroll
  for (int m_ = 0; m_ < 8; ++m_) {
#pragma unroll
    for (int r = 0; r < 4; ++r) {
      float v = bnv[0] - 2.0f * acc[m_][0][r];
      v = fminf(v, bnv[1] - 2.0f * acc[m_][1][r]);
      v = fminf(v, bnv[2] - 2.0f * acc[m_][2][r]);
      v = fminf(v, bnv[3] - 2.0f * acc[m_][3][r]);
      // C/D layout: col = lane&15, row = (lane>>4)*4 + r
      v = fminf(v, __shfl_xor(v, 1));
      v = fminf(v, __shfl_xor(v, 2));
      v = fminf(v, __shfl_xor(v, 4));
      v = fminf(v, __shfl_xor(v, 8));
      if (lr == 0) {
        int q = qbase + m_ * 16 + (lane >> 4) * 4 + r;
        atomicMin(&minbits[q], __float_as_uint(v));  // positive floats: uint order == float order
      }
    }
  }
}

// ---- patch scores + per-image max -------------------------------------
__global__ void scores_kernel(const uint32_t* __restrict__ minbits, const float* __restrict__ qn,
                              float* __restrict__ ps, float* __restrict__ img) {
  int q = blockIdx.x * 256 + threadIdx.x;
  if (q >= NQ) return;
  float s = __uint_as_float(minbits[q]) + qn[q];
  ps[q] = s;
  atomicMax((uint32_t*)&img[q / 784], __float_as_uint(s));  // scores > 0
}

// ---- bilinear 28x28 -> 224x224 (half-pixel centers, edge clamp) -------
__global__ void resize_kernel(const float* __restrict__ ps, float* __restrict__ masks) {
  int idx = blockIdx.x * 256 + threadIdx.x;
  if (idx >= NPIX) return;
  int b   = idx / (224 * 224);
  int rem = idx - b * (224 * 224);
  int oy  = rem / 224;
  int ox  = rem - oy * 224;
  float sy = (oy + 0.5f) * 0.125f - 0.5f;
  float sx = (ox + 0.5f) * 0.125f - 0.5f;
  float fy0 = floorf(sy), fx0 = floorf(sx);
  int y0 = (int)fy0, x0 = (int)fx0;
  float fy = sy - fy0, fx = sx - fx0;
  int y0c = min(max(y0, 0), 27),     y1c = min(max(y0 + 1, 0), 27);
  int x0c = min(max(x0, 0), 27),     x1c = min(max(x0 + 1, 0), 27);
  const float* p = ps + b * 784;
  float top = p[y0c * 28 + x0c] * (1.f - fx) + p[y0c * 28 + x1c] * fx;
  float bot = p[y1c * 28 + x0c] * (1.f - fx) + p[y1c * 28 + x1c] * fx;
  masks[idx] = top * (1.f - fy) + bot * fy;
}

// ---- host launch -------------------------------------------------------
extern "C" void kernel_launch(void* const* d_in, const int* in_sizes, int n_in,
                              void* d_out, int out_size, void* d_ws, size_t ws_size,
                              hipStream_t stream) {
  const float* features = (const float*)d_in[0];   // [6272, 1536]
  const float* bank     = (const float*)d_in[1];   // [50000, 1536]

  char* ws = (char*)d_ws;
  size_t off = 0;
  unsigned short* bankB = (unsigned short*)(ws + off); off += (size_t)NBP2 * DIM * 2;  // 154.1 MB
  unsigned short* featB = (unsigned short*)(ws + off); off += (size_t)NQP * DIM * 2;   // 19.7 MB
  float*    bn      = (float*)(ws + off);    off += (size_t)NBP2 * 4;
  float*    qn      = (float*)(ws + off);    off += (size_t)NQP * 4;
  uint32_t* minbits = (uint32_t*)(ws + off); off += (size_t)NQP * 4;
  float*    ps      = (float*)(ws + off);    off += (size_t)NQ * 4;

  float* out_scores = (float*)d_out;       // [8]
  float* masks      = out_scores + 8;      // [8,224,224]

  hipLaunchKernelGGL(init_kernel, dim3(25), dim3(256), 0, stream, minbits, out_scores);
  hipLaunchKernelGGL(conv_rows, dim3(NBP2 / 4), dim3(256), 0, stream, bank, bankB, bn, NB, NBP2);
  hipLaunchKernelGGL(conv_rows, dim3(NQP / 4), dim3(256), 0, stream, features, featB, qn, NQ, NQP);
  hipLaunchKernelGGL(gemm_min8, dim3(GRID2), dim3(512), 0, stream, featB, bankB, bn, minbits);
  hipLaunchKernelGGL(scores_kernel, dim3(25), dim3(256), 0, stream, minbits, qn, ps, out_scores);
  hipLaunchKernelGGL(resize_kernel, dim3((NPIX + 255) / 256), dim3(256), 0, stream, ps, masks);
}